// Round 10
// baseline (261.847 us; speedup 1.0000x reference)
//
#include <hip/hip_runtime.h>
#include <hip/hip_bf16.h>
#include <math.h>

#define S_LEN 2048
#define EMB   1024
#define HEADS 16
#define HDIM  64
#define SPLIT 4

#define C_SCALE   0.045084439f
#define BIAS_OK  -2.0f

#define NE  ((size_t)2 * S_LEN * EMB)
#define NL  ((size_t)2 * S_LEN * HEADS)
#define NMB ((size_t)2 * S_LEN * S_LEN / 64)

typedef __bf16 bf16x8 __attribute__((ext_vector_type(8)));
typedef float  f32x4  __attribute__((ext_vector_type(4)));
typedef float  f32x16 __attribute__((ext_vector_type(16)));

__device__ __forceinline__ bf16x8 cvt8(const float* v) {
    bf16x8 r;
#pragma unroll
    for (int i = 0; i < 8; ++i) r[i] = (__bf16)v[i];
    return r;
}
__device__ __forceinline__ unsigned long long pack4(float a, float b, float c, float d) {
    __bf16 t[4] = {(__bf16)a, (__bf16)b, (__bf16)c, (__bf16)d};
    return *(unsigned long long*)t;
}
__device__ __forceinline__ bf16x8 cat2(unsigned long long lo, unsigned long long hi) {
    unsigned long long t[2] = {lo, hi};
    return *(bf16x8*)t;
}
__device__ __forceinline__ void gld_lds16(const void* g, void* l) {
    __builtin_amdgcn_global_load_lds(
        (const __attribute__((address_space(1))) void*)g,
        (__attribute__((address_space(3))) void*)l, 16, 0, 0);
}

// ---------------- Pre-pass: cvt W + bit-pack mask (natural k-order) ----------------
__global__ __launch_bounds__(256)
void prepass_kernel(const float* __restrict__ Wf, const int* __restrict__ Mp,
                    __bf16* __restrict__ Wb, unsigned long long* __restrict__ Mb) {
    const int bid = blockIdx.x, tid = threadIdx.x;
    if (bid < 512) {
        size_t i = ((size_t)bid * 256 + tid) * 8;
        float t[8];
        *(float4*)&t[0] = *(const float4*)(Wf + i);
        *(float4*)&t[4] = *(const float4*)(Wf + i + 4);
        *(bf16x8*)(Wb + i) = cvt8(t);
    } else {
        const int w = tid >> 6, lane = tid & 63;
        const int wg = (bid - 512) * 4 + w;
#pragma unroll 4
        for (int it = 0; it < 64; ++it) {
            size_t W = (size_t)wg * 64 + it;
            int v = Mp[W * 64 + lane];
            unsigned long long b = __ballot(v != 0);
            if (lane == 0) Mb[W] = b;
        }
    }
}

// ---------------- Attention probe family (V0 = real) ----------------
// V0: full.  V1: stage-only.  V2: compute-only (stage once).  V3: full minus exp/mask.
template<int V>
__global__ __launch_bounds__(256, 4)
void attn_probe(const float* __restrict__ Vp, const float* __restrict__ Kp,
                const float* __restrict__ Qp, const unsigned long long* __restrict__ Mb,
                __bf16* __restrict__ Opart, float* __restrict__ Lpart,
                unsigned long long* __restrict__ Dummy) {
    __shared__ __bf16 Klds[64 * 64];
    __shared__ __bf16 Vtlds[64 * 64];

    const int tid  = threadIdx.x;
    const int lane = tid & 63;
    const int w    = tid >> 6;
    const int nblk = 2 * HEADS * SPLIT * 16;
    const int bid  = (blockIdx.x & 7) * (nblk / 8) + (blockIdx.x >> 3);
    const int qt = bid & 15;
    const int sp = (bid >> 4) & (SPLIT - 1);
    const int h  = (bid >> 6) & 15;
    const int n  = bid >> 10;

    const int ql = lane & 31;
    const int g  = lane >> 5;

    const float* qbase = Qp + (size_t)n * S_LEN * EMB + h * HDIM;
    const float* kbase = Kp + (size_t)n * S_LEN * EMB + h * HDIM;
    const float* vbase = Vp + (size_t)n * S_LEN * EMB + h * HDIM;

    const int q = qt * 128 + w * 32 + ql;

    bf16x8 qfrag[4];
    if constexpr (V != 1) {
#pragma unroll
        for (int ds_ = 0; ds_ < 4; ++ds_) {
            const float* qp = qbase + (size_t)q * EMB + ds_ * 16 + g * 8;
            float tmp[8];
            *(float4*)&tmp[0] = *(const float4*)qp;
            *(float4*)&tmp[4] = *(const float4*)(qp + 4);
            qfrag[ds_] = cvt8(tmp);
        }
    }

    f32x16 oacc[2] = {};
    float la = 0.f;
    int keep = 0;

    const unsigned long long* mrow = Mb + ((size_t)(n * S_LEN + q) << 5);

    const int sk  = tid >> 2;
    const int sdq = (tid & 3) * 16;
    const int d0  = (tid & 31) * 2;
    const int kv8 = (tid >> 5) * 8;

    const int kvbase = sp * (S_LEN / SPLIT);
    const int niter  = (S_LEN / SPLIT) / 64;

#define STAGE(KV0) do {                                                               \
        const float* kp = kbase + (size_t)((KV0) + sk) * EMB + sdq;                   \
        float tk[16];                                                                 \
        *(float4*)&tk[0]  = *(const float4*)kp;                                       \
        *(float4*)&tk[4]  = *(const float4*)(kp + 4);                                 \
        *(float4*)&tk[8]  = *(const float4*)(kp + 8);                                 \
        *(float4*)&tk[12] = *(const float4*)(kp + 12);                                \
        *(bf16x8*)((char*)Klds + sk * 128 + ((sdq * 2)       ^ ((sk & 7) << 4))) = cvt8(&tk[0]); \
        *(bf16x8*)((char*)Klds + sk * 128 + (((sdq + 8) * 2) ^ ((sk & 7) << 4))) = cvt8(&tk[8]); \
        const float* vp = vbase + (size_t)((KV0) + kv8) * EMB + d0;                   \
        float r0[8], r1[8];                                                           \
        _Pragma("unroll")                                                             \
        for (int j = 0; j < 8; ++j) {                                                 \
            float2 tv = *(const float2*)(vp + (size_t)j * EMB);                       \
            r0[j] = tv.x; r1[j] = tv.y;                                               \
        }                                                                             \
        *(bf16x8*)((char*)Vtlds + d0 * 128       + ((kv8 * 2) ^ ((d0 & 7) << 4)))       = cvt8(r0); \
        *(bf16x8*)((char*)Vtlds + (d0 + 1) * 128 + ((kv8 * 2) ^ (((d0 + 1) & 7) << 4))) = cvt8(r1); \
    } while (0)

    if constexpr (V == 2) STAGE(kvbase);

#pragma unroll 1
    for (int t = 0; t < niter; ++t) {
        const int kv0 = kvbase + t * 64;
        __syncthreads();
        if constexpr (V != 2) STAGE(kv0);
        __syncthreads();

        if constexpr (V == 1) {
            int a = *(const int*)((char*)Klds + ((tid * 8) & 8191));
            int b = *(const int*)((char*)Vtlds + ((tid * 8) & 8191));
            asm volatile("" :: "v"(a), "v"(b));
            keep ^= a ^ b;
            continue;
        } else {
            unsigned long long m64 = 0;
            if constexpr (V != 3) m64 = mrow[kv0 >> 6];

#pragma unroll
            for (int kt = 0; kt < 2; ++kt) {
                f32x16 E = {};
                __builtin_amdgcn_s_setprio(1);
#pragma unroll
                for (int ds_ = 0; ds_ < 4; ++ds_) {
                    int row = kt * 32 + ql;
                    bf16x8 kf = *(const bf16x8*)((char*)Klds + row * 128 +
                        ((ds_ * 32 + g * 16) ^ ((row & 7) << 4)));
                    E = __builtin_amdgcn_mfma_f32_32x32x16_bf16(kf, qfrag[ds_], E, 0, 0, 0);
                }
                __builtin_amdgcn_s_setprio(0);

                unsigned long long own[4];
                if constexpr (V == 3) {
#pragma unroll
                    for (int rq = 0; rq < 4; ++rq)
                        own[rq] = pack4(fmaf(E[4*rq+0], C_SCALE, BIAS_OK),
                                        fmaf(E[4*rq+1], C_SCALE, BIAS_OK),
                                        fmaf(E[4*rq+2], C_SCALE, BIAS_OK),
                                        fmaf(E[4*rq+3], C_SCALE, BIAS_OK));
                } else {
                    const unsigned u = (unsigned)(m64 >> (kt * 32 + 4 * g));
#pragma unroll
                    for (int rq = 0; rq < 4; ++rq) {
                        unsigned nib = u >> (8 * rq);
                        float p0 = __builtin_amdgcn_exp2f(fmaf(E[4*rq+0], C_SCALE, BIAS_OK)) * (float)(nib & 1u);
                        float p1 = __builtin_amdgcn_exp2f(fmaf(E[4*rq+1], C_SCALE, BIAS_OK)) * (float)((nib >> 1) & 1u);
                        float p2 = __builtin_amdgcn_exp2f(fmaf(E[4*rq+2], C_SCALE, BIAS_OK)) * (float)((nib >> 2) & 1u);
                        float p3 = __builtin_amdgcn_exp2f(fmaf(E[4*rq+3], C_SCALE, BIAS_OK)) * (float)((nib >> 3) & 1u);
                        la += (p0 + p1) + (p2 + p3);
                        own[rq] = pack4(p0, p1, p2, p3);
                    }
                }

                unsigned long long sa = g ? own[0] : own[1];
                unsigned long long sb = g ? own[2] : own[3];
                unsigned long long ra = __shfl_xor((long long)sa, 32);
                unsigned long long rb = __shfl_xor((long long)sb, 32);
                bf16x8 frag0 = g ? cat2(ra, own[1]) : cat2(own[0], ra);
                bf16x8 frag1 = g ? cat2(rb, own[3]) : cat2(own[2], rb);

                __builtin_amdgcn_s_setprio(1);
#pragma unroll
                for (int dt = 0; dt < 2; ++dt) {
                    int row = dt * 32 + ql;
                    bf16x8 v0 = *(const bf16x8*)((char*)Vtlds + row * 128 +
                        (((2*kt) * 32 + g * 16) ^ ((row & 7) << 4)));
                    bf16x8 v1 = *(const bf16x8*)((char*)Vtlds + row * 128 +
                        (((2*kt+1) * 32 + g * 16) ^ ((row & 7) << 4)));
                    oacc[dt] = __builtin_amdgcn_mfma_f32_32x32x16_bf16(v0, frag0, oacc[dt], 0, 0, 0);
                    oacc[dt] = __builtin_amdgcn_mfma_f32_32x32x16_bf16(v1, frag1, oacc[dt], 0, 0, 0);
                }
                __builtin_amdgcn_s_setprio(0);
            }
        }
    }
#undef STAGE

    if constexpr (V == 0) {
        float lt = la + __shfl_xor(la, 32);
        __bf16* op = Opart + (size_t)sp * NE + ((size_t)n * S_LEN + q) * EMB + h * HDIM;
#pragma unroll
        for (int dt = 0; dt < 2; ++dt)
#pragma unroll
            for (int rq = 0; rq < 4; ++rq)
                *(unsigned long long*)(op + dt * 32 + 8 * rq + 4 * g) =
                    pack4(oacc[dt][4*rq], oacc[dt][4*rq+1], oacc[dt][4*rq+2], oacc[dt][4*rq+3]);
        if (g == 0)
            Lpart[(size_t)sp * NL + ((size_t)n * S_LEN + q) * HEADS + h] = lt;
    } else if constexpr (V == 1) {
        Dummy[(size_t)blockIdx.x * 256 + tid] = (unsigned long long)(unsigned)keep;
    } else {
        Dummy[(size_t)blockIdx.x * 256 + tid] =
            pack4(oacc[0][0], oacc[0][1], oacc[0][2], oacc[0][3]) ^
            (unsigned long long)(int)la;
    }
}

// ---------------- Reduce: X = (sum_s O_s) / (sum_s l_s); X aliases Opart[0] ----------
__global__ __launch_bounds__(256)
void reduce_kernel(const __bf16* __restrict__ Opart, const float* __restrict__ Lpart,
                   __bf16* __restrict__ X) {
    size_t e0 = ((size_t)blockIdx.x * 256 + threadIdx.x) * 8;
    size_t hr = e0 >> 6;
    float l = 0.f;
#pragma unroll
    for (int s = 0; s < SPLIT; ++s) l += Lpart[s * NL + hr];
    float inv = 1.f / l;
    float acc[8] = {};
#pragma unroll
    for (int s = 0; s < SPLIT; ++s) {
        bf16x8 v = *(const bf16x8*)(Opart + s * NE + e0);
#pragma unroll
        for (int i = 0; i < 8; ++i) acc[i] += (float)v[i];
    }
    bf16x8 r;
#pragma unroll
    for (int i = 0; i < 8; ++i) r[i] = (__bf16)(acc[i] * inv);
    *(bf16x8*)(X + e0) = r;
}

// ---------------- FC kernel ----------------
__global__ __launch_bounds__(256)
void fc_kernel(const __bf16* __restrict__ X, const __bf16* __restrict__ Wb,
               const float* __restrict__ bfc, float* __restrict__ Out) {
    __shared__ __bf16 Al[128 * 32];
    __shared__ __bf16 Bl[128 * 32];
    const int tid = threadIdx.x, lane = tid & 63, w = tid >> 6;
    const int ql = lane & 15, g = lane >> 4;
    const int bm = blockIdx.x >> 3, bn = blockIdx.x & 7;
    const int wr = w >> 1, wc = w & 1;

    const int rowL = lane >> 2;
    const int colE = (lane & 3) * 8;

    f32x4 acc[4][4] = {};

    for (int k0 = 0; k0 < EMB; k0 += 32) {
        __syncthreads();
        const int q0 = w * 2, q1 = w * 2 + 1;
        gld_lds16(X  + (size_t)(bm * 128 + q0 * 16 + rowL) * EMB + k0 + colE, Al + q0 * 512);
        gld_lds16(X  + (size_t)(bm * 128 + q1 * 16 + rowL) * EMB + k0 + colE, Al + q1 * 512);
        gld_lds16(Wb + (size_t)(bn * 128 + q0 * 16 + rowL) * EMB + k0 + colE, Bl + q0 * 512);
        gld_lds16(Wb + (size_t)(bn * 128 + q1 * 16 + rowL) * EMB + k0 + colE, Bl + q1 * 512);
        __syncthreads();

        bf16x8 a[4], b[4];
#pragma unroll
        for (int mi = 0; mi < 4; ++mi)
            a[mi] = *(const bf16x8*)(Al + (wr * 64 + mi * 16 + ql) * 32 + g * 8);
#pragma unroll
        for (int nj = 0; nj < 4; ++nj)
            b[nj] = *(const bf16x8*)(Bl + (wc * 64 + nj * 16 + ql) * 32 + g * 8);
#pragma unroll
        for (int mi = 0; mi < 4; ++mi)
#pragma unroll
            for (int nj = 0; nj < 4; ++nj)
                acc[mi][nj] = __builtin_amdgcn_mfma_f32_16x16x32_bf16(a[mi], b[nj], acc[mi][nj], 0, 0, 0);
    }

#pragma unroll
    for (int nj = 0; nj < 4; ++nj) {
        int col = bn * 128 + wc * 64 + nj * 16 + ql;
        float bias = bfc[col];
#pragma unroll
        for (int mi = 0; mi < 4; ++mi) {
            int row0 = bm * 128 + wr * 64 + mi * 16 + g * 4;
#pragma unroll
            for (int r = 0; r < 4; ++r)
                Out[(size_t)(row0 + r) * EMB + col] = acc[mi][nj][r] + bias;
        }
    }
}

extern "C" void kernel_launch(void* const* d_in, const int* in_sizes, int n_in,
                              void* d_out, int out_size, void* d_ws, size_t ws_size,
                              hipStream_t stream) {
    const float* Vp = (const float*)d_in[0];
    const float* Kp = (const float*)d_in[1];
    const float* Qp = (const float*)d_in[2];
    const int*   Mp = (const int*)d_in[3];
    const float* Wf = (const float*)d_in[4];
    const float* bf = (const float*)d_in[5];
    float* Out = (float*)d_out;

    char* p = (char*)d_ws;
    __bf16* Opart = (__bf16*)p;             p += SPLIT * NE * 2;        // 32 MB
    float*  Lpart = (float*)p;              p += SPLIT * NL * 4;        // 1 MB
    __bf16* Wb    = (__bf16*)p;             p += (size_t)EMB * EMB * 2; // 2 MB
    unsigned long long* Mb = (unsigned long long*)p; p += NMB * 8;      // 1 MB
    unsigned long long* Dummy = (unsigned long long*)p;                 // 4 MB

    const dim3 agrid(2 * HEADS * SPLIT * 16), ablk(256);

    prepass_kernel<<<dim3(1024), dim3(256), 0, stream>>>(Wf, Mp, Wb, Mb);
    // ---- diagnostic probes (outputs go to Dummy; rocprof reports their durations) ----
    attn_probe<1><<<agrid, ablk, 0, stream>>>(Vp, Kp, Qp, Mb, Opart, Lpart, Dummy);
    attn_probe<2><<<agrid, ablk, 0, stream>>>(Vp, Kp, Qp, Mb, Opart, Lpart, Dummy);
    attn_probe<3><<<agrid, ablk, 0, stream>>>(Vp, Kp, Qp, Mb, Opart, Lpart, Dummy);
    // ---- real attention ----
    attn_probe<0><<<agrid, ablk, 0, stream>>>(Vp, Kp, Qp, Mb, Opart, Lpart, Dummy);
    reduce_kernel<<<dim3(NE / 8 / 256), dim3(256), 0, stream>>>(Opart, Lpart, Opart);
    fc_kernel<<<dim3((2 * S_LEN / 128) * (EMB / 128)), dim3(256), 0, stream>>>(Opart, Wb, bf, Out);
}

// Round 11
// 175.355 us; speedup vs baseline: 1.4932x; 1.4932x over previous
//
#include <hip/hip_runtime.h>
#include <hip/hip_bf16.h>
#include <math.h>

#define S_LEN 2048
#define EMB   1024
#define HEADS 16
#define HDIM  64
#define SPLIT 4
#define NITER ((S_LEN / SPLIT) / 64)   // 8

#define C_SCALE   0.045084439f
#define BIAS_OK  -2.0f

#define NE  ((size_t)2 * S_LEN * EMB)
#define NL  ((size_t)2 * S_LEN * HEADS)
#define NMB ((size_t)2 * S_LEN * S_LEN / 64)

typedef __bf16 bf16x8 __attribute__((ext_vector_type(8)));
typedef float  f32x4  __attribute__((ext_vector_type(4)));
typedef float  f32x16 __attribute__((ext_vector_type(16)));

__device__ __forceinline__ bf16x8 cvt8(const float* v) {
    bf16x8 r;
#pragma unroll
    for (int i = 0; i < 8; ++i) r[i] = (__bf16)v[i];
    return r;
}
__device__ __forceinline__ unsigned long long pack4(float a, float b, float c, float d) {
    __bf16 t[4] = {(__bf16)a, (__bf16)b, (__bf16)c, (__bf16)d};
    return *(unsigned long long*)t;
}
__device__ __forceinline__ bf16x8 cat2(unsigned long long lo, unsigned long long hi) {
    unsigned long long t[2] = {lo, hi};
    return *(bf16x8*)t;
}
__device__ __forceinline__ void gld_lds16(const void* g, void* l) {
    __builtin_amdgcn_global_load_lds(
        (const __attribute__((address_space(1))) void*)g,
        (__attribute__((address_space(3))) void*)l, 16, 0, 0);
}

// ---------------- Pre-pass: cvt W + bit-pack mask (natural k-order) ----------------
__global__ __launch_bounds__(256)
void prepass_kernel(const float* __restrict__ Wf, const int* __restrict__ Mp,
                    __bf16* __restrict__ Wb, unsigned long long* __restrict__ Mb) {
    const int bid = blockIdx.x, tid = threadIdx.x;
    if (bid < 512) {
        size_t i = ((size_t)bid * 256 + tid) * 8;
        float t[8];
        *(float4*)&t[0] = *(const float4*)(Wf + i);
        *(float4*)&t[4] = *(const float4*)(Wf + i + 4);
        *(bf16x8*)(Wb + i) = cvt8(t);
    } else {
        const int w = tid >> 6, lane = tid & 63;
        const int wg = (bid - 512) * 4 + w;
#pragma unroll 4
        for (int it = 0; it < 64; ++it) {
            size_t W = (size_t)wg * 64 + it;
            int v = Mp[W * 64 + lane];
            unsigned long long b = __ballot(v != 0);
            if (lane == 0) Mb[W] = b;
        }
    }
}

// ------- Attention: 32x32 MFMA, in-reg softmax, KV-split, T14 pipelined staging -------
__global__ __launch_bounds__(256, 4)
void attn_kernel(const float* __restrict__ Vp, const float* __restrict__ Kp,
                 const float* __restrict__ Qp, const unsigned long long* __restrict__ Mb,
                 __bf16* __restrict__ Opart, float* __restrict__ Lpart) {
    __shared__ __bf16 Klds[2][64 * 64];    // double-buffered, XOR-swizzled, 16KB
    __shared__ __bf16 Vtlds[2][64 * 64];   // double-buffered, XOR-swizzled, 16KB

    const int tid  = threadIdx.x;
    const int lane = tid & 63;
    const int w    = tid >> 6;
    const int nblk = 2 * HEADS * SPLIT * 16;
    const int bid  = (blockIdx.x & 7) * (nblk / 8) + (blockIdx.x >> 3); // XCD chunked swizzle
    const int qt = bid & 15;
    const int sp = (bid >> 4) & (SPLIT - 1);
    const int h  = (bid >> 6) & 15;
    const int n  = bid >> 10;

    const int ql = lane & 31;
    const int g  = lane >> 5;

    const float* qbase = Qp + (size_t)n * S_LEN * EMB + h * HDIM;
    const float* kbase = Kp + (size_t)n * S_LEN * EMB + h * HDIM;
    const float* vbase = Vp + (size_t)n * S_LEN * EMB + h * HDIM;

    const int q = qt * 128 + w * 32 + ql;

    // Q fragments (B operand, 32x32x16)
    bf16x8 qfrag[4];
#pragma unroll
    for (int ds_ = 0; ds_ < 4; ++ds_) {
        const float* qp = qbase + (size_t)q * EMB + ds_ * 16 + g * 8;
        float tmp[8];
        *(float4*)&tmp[0] = *(const float4*)qp;
        *(float4*)&tmp[4] = *(const float4*)(qp + 4);
        qfrag[ds_] = cvt8(tmp);
    }

    f32x16 oacc[2] = {};
    float la = 0.f;

    const unsigned long long* mrow = Mb + ((size_t)(n * S_LEN + q) << 5) + sp * NITER;

    const int sk  = tid >> 2;          // K row 0..63
    const int sdq = (tid & 3) * 16;    // K col base
    const int d0  = (tid & 31) * 2;    // Vt d pair
    const int kv8 = (tid >> 5) * 8;    // Vt kv octet

    const int kvbase = sp * (S_LEN / SPLIT);

    float kreg[16], vreg[16];

#define LOADKV(T) do {                                                                \
        const float* kp_ = kbase + (size_t)(kvbase + (T) * 64 + sk) * EMB + sdq;      \
        *(float4*)&kreg[0]  = *(const float4*)kp_;                                    \
        *(float4*)&kreg[4]  = *(const float4*)(kp_ + 4);                              \
        *(float4*)&kreg[8]  = *(const float4*)(kp_ + 8);                              \
        *(float4*)&kreg[12] = *(const float4*)(kp_ + 12);                             \
        const float* vp_ = vbase + (size_t)(kvbase + (T) * 64 + kv8) * EMB + d0;      \
        _Pragma("unroll")                                                             \
        for (int j = 0; j < 8; ++j)                                                   \
            *(float2*)&vreg[j * 2] = *(const float2*)(vp_ + (size_t)j * EMB);         \
    } while (0)

#define WRITEKV(B) do {                                                               \
        *(bf16x8*)((char*)Klds[B] + sk * 128 + ((sdq * 2)       ^ ((sk & 7) << 4))) = cvt8(&kreg[0]); \
        *(bf16x8*)((char*)Klds[B] + sk * 128 + (((sdq + 8) * 2) ^ ((sk & 7) << 4))) = cvt8(&kreg[8]); \
        float r0_[8], r1_[8];                                                         \
        _Pragma("unroll")                                                             \
        for (int j = 0; j < 8; ++j) { r0_[j] = vreg[2 * j]; r1_[j] = vreg[2 * j + 1]; } \
        *(bf16x8*)((char*)Vtlds[B] + d0 * 128       + ((kv8 * 2) ^ ((d0 & 7) << 4)))       = cvt8(r0_); \
        *(bf16x8*)((char*)Vtlds[B] + (d0 + 1) * 128 + ((kv8 * 2) ^ (((d0 + 1) & 7) << 4))) = cvt8(r1_); \
    } while (0)

    // prologue: tile 0 staged (pays latency once)
    LOADKV(0);
    WRITEKV(0);
    __syncthreads();

#pragma unroll 1
    for (int t = 0; t < NITER; ++t) {
        const int buf = t & 1;
        // issue next tile's global loads FIRST — latency hides under compute below
        if (t < NITER - 1) LOADKV(t + 1);
        const unsigned long long m64 = mrow[t];

#pragma unroll
        for (int kt = 0; kt < 2; ++kt) {
            // QK^T swapped 32x32: E[k_local][q]
            f32x16 E = {};
            __builtin_amdgcn_s_setprio(1);
#pragma unroll
            for (int ds_ = 0; ds_ < 4; ++ds_) {
                int row = kt * 32 + ql;
                bf16x8 kf = *(const bf16x8*)((char*)Klds[buf] + row * 128 +
                    ((ds_ * 32 + g * 16) ^ ((row & 7) << 4)));
                E = __builtin_amdgcn_mfma_f32_32x32x16_bf16(kf, qfrag[ds_], E, 0, 0, 0);
            }
            __builtin_amdgcn_s_setprio(0);

            // in-register softmax: p = exp2(e*C - 2) * maskbit
            const unsigned u = (unsigned)(m64 >> (kt * 32 + 4 * g));
            unsigned long long own[4];
#pragma unroll
            for (int rq = 0; rq < 4; ++rq) {
                unsigned nib = u >> (8 * rq);
                float p0 = __builtin_amdgcn_exp2f(fmaf(E[4*rq+0], C_SCALE, BIAS_OK)) * (float)(nib & 1u);
                float p1 = __builtin_amdgcn_exp2f(fmaf(E[4*rq+1], C_SCALE, BIAS_OK)) * (float)((nib >> 1) & 1u);
                float p2 = __builtin_amdgcn_exp2f(fmaf(E[4*rq+2], C_SCALE, BIAS_OK)) * (float)((nib >> 2) & 1u);
                float p3 = __builtin_amdgcn_exp2f(fmaf(E[4*rq+3], C_SCALE, BIAS_OK)) * (float)((nib >> 3) & 1u);
                la += (p0 + p1) + (p2 + p3);
                own[rq] = pack4(p0, p1, p2, p3);
            }

            // cross-half exchange -> PV B-frags
            unsigned long long sa = g ? own[0] : own[1];
            unsigned long long sb = g ? own[2] : own[3];
            unsigned long long ra = __shfl_xor((long long)sa, 32);
            unsigned long long rb = __shfl_xor((long long)sb, 32);
            bf16x8 frag0 = g ? cat2(ra, own[1]) : cat2(own[0], ra);
            bf16x8 frag1 = g ? cat2(rb, own[3]) : cat2(own[2], rb);

            // PV swapped 32x32
            __builtin_amdgcn_s_setprio(1);
#pragma unroll
            for (int dt = 0; dt < 2; ++dt) {
                int row = dt * 32 + ql;
                bf16x8 v0 = *(const bf16x8*)((char*)Vtlds[buf] + row * 128 +
                    (((2*kt) * 32 + g * 16) ^ ((row & 7) << 4)));
                bf16x8 v1 = *(const bf16x8*)((char*)Vtlds[buf] + row * 128 +
                    (((2*kt+1) * 32 + g * 16) ^ ((row & 7) << 4)));
                oacc[dt] = __builtin_amdgcn_mfma_f32_32x32x16_bf16(v0, frag0, oacc[dt], 0, 0, 0);
                oacc[dt] = __builtin_amdgcn_mfma_f32_32x32x16_bf16(v1, frag1, oacc[dt], 0, 0, 0);
            }
            __builtin_amdgcn_s_setprio(0);
        }

        // write next tile into the OTHER buffer (loads long since returned), then sync
        if (t < NITER - 1) WRITEKV(buf ^ 1);
        __syncthreads();
    }
#undef LOADKV
#undef WRITEKV

    // epilogue: UNNORMALIZED partial O (bf16) + partial l (f32)
    float lt = la + __shfl_xor(la, 32);
    __bf16* op = Opart + (size_t)sp * NE + ((size_t)n * S_LEN + q) * EMB + h * HDIM;
#pragma unroll
    for (int dt = 0; dt < 2; ++dt)
#pragma unroll
        for (int rq = 0; rq < 4; ++rq)
            *(unsigned long long*)(op + dt * 32 + 8 * rq + 4 * g) =
                pack4(oacc[dt][4*rq], oacc[dt][4*rq+1], oacc[dt][4*rq+2], oacc[dt][4*rq+3]);
    if (g == 0)
        Lpart[(size_t)sp * NL + ((size_t)n * S_LEN + q) * HEADS + h] = lt;
}

// ---------------- Reduce: X = (sum_s O_s) / (sum_s l_s); X aliases Opart[0] ----------
__global__ __launch_bounds__(256)
void reduce_kernel(const __bf16* __restrict__ Opart, const float* __restrict__ Lpart,
                   __bf16* __restrict__ X) {
    size_t e0 = ((size_t)blockIdx.x * 256 + threadIdx.x) * 8;
    size_t hr = e0 >> 6;
    float l = 0.f;
#pragma unroll
    for (int s = 0; s < SPLIT; ++s) l += Lpart[s * NL + hr];
    float inv = 1.f / l;
    float acc[8] = {};
#pragma unroll
    for (int s = 0; s < SPLIT; ++s) {
        bf16x8 v = *(const bf16x8*)(Opart + s * NE + e0);
#pragma unroll
        for (int i = 0; i < 8; ++i) acc[i] += (float)v[i];
    }
    bf16x8 r;
#pragma unroll
    for (int i = 0; i < 8; ++i) r[i] = (__bf16)(acc[i] * inv);
    *(bf16x8*)(X + e0) = r;
}

// ---------------- FC kernel: Out = X @ W^T + b (128x128 tile, global_load_lds) -------
__global__ __launch_bounds__(256)
void fc_kernel(const __bf16* __restrict__ X, const __bf16* __restrict__ Wb,
               const float* __restrict__ bfc, float* __restrict__ Out) {
    __shared__ __bf16 Al[128 * 32];
    __shared__ __bf16 Bl[128 * 32];
    const int tid = threadIdx.x, lane = tid & 63, w = tid >> 6;
    const int ql = lane & 15, g = lane >> 4;
    const int bm = blockIdx.x >> 3, bn = blockIdx.x & 7;
    const int wr = w >> 1, wc = w & 1;

    const int rowL = lane >> 2;
    const int colE = (lane & 3) * 8;

    f32x4 acc[4][4] = {};

    for (int k0 = 0; k0 < EMB; k0 += 32) {
        __syncthreads();
        const int q0 = w * 2, q1 = w * 2 + 1;
        gld_lds16(X  + (size_t)(bm * 128 + q0 * 16 + rowL) * EMB + k0 + colE, Al + q0 * 512);
        gld_lds16(X  + (size_t)(bm * 128 + q1 * 16 + rowL) * EMB + k0 + colE, Al + q1 * 512);
        gld_lds16(Wb + (size_t)(bn * 128 + q0 * 16 + rowL) * EMB + k0 + colE, Bl + q0 * 512);
        gld_lds16(Wb + (size_t)(bn * 128 + q1 * 16 + rowL) * EMB + k0 + colE, Bl + q1 * 512);
        __syncthreads();

        bf16x8 a[4], b[4];
#pragma unroll
        for (int mi = 0; mi < 4; ++mi)
            a[mi] = *(const bf16x8*)(Al + (wr * 64 + mi * 16 + ql) * 32 + g * 8);
#pragma unroll
        for (int nj = 0; nj < 4; ++nj)
            b[nj] = *(const bf16x8*)(Bl + (wc * 64 + nj * 16 + ql) * 32 + g * 8);
#pragma unroll
        for (int mi = 0; mi < 4; ++mi)
#pragma unroll
            for (int nj = 0; nj < 4; ++nj)
                acc[mi][nj] = __builtin_amdgcn_mfma_f32_16x16x32_bf16(a[mi], b[nj], acc[mi][nj], 0, 0, 0);
    }

#pragma unroll
    for (int nj = 0; nj < 4; ++nj) {
        int col = bn * 128 + wc * 64 + nj * 16 + ql;
        float bias = bfc[col];
#pragma unroll
        for (int mi = 0; mi < 4; ++mi) {
            int row0 = bm * 128 + wr * 64 + mi * 16 + g * 4;
#pragma unroll
            for (int r = 0; r < 4; ++r)
                Out[(size_t)(row0 + r) * EMB + col] = acc[mi][nj][r] + bias;
        }
    }
}

extern "C" void kernel_launch(void* const* d_in, const int* in_sizes, int n_in,
                              void* d_out, int out_size, void* d_ws, size_t ws_size,
                              hipStream_t stream) {
    const float* Vp = (const float*)d_in[0];
    const float* Kp = (const float*)d_in[1];
    const float* Qp = (const float*)d_in[2];
    const int*   Mp = (const int*)d_in[3];
    const float* Wf = (const float*)d_in[4];
    const float* bf = (const float*)d_in[5];
    float* Out = (float*)d_out;

    char* p = (char*)d_ws;
    __bf16* Opart = (__bf16*)p;             p += SPLIT * NE * 2;        // 32 MB; X aliases Opart[0]
    float*  Lpart = (float*)p;              p += SPLIT * NL * 4;        // 1 MB
    __bf16* Wb    = (__bf16*)p;             p += (size_t)EMB * EMB * 2; // 2 MB
    unsigned long long* Mb = (unsigned long long*)p;                    // 1 MB

    prepass_kernel<<<dim3(1024), dim3(256), 0, stream>>>(Wf, Mp, Wb, Mb);
    attn_kernel<<<dim3(2 * HEADS * SPLIT * 16), dim3(256), 0, stream>>>(Vp, Kp, Qp, Mb, Opart, Lpart);
    reduce_kernel<<<dim3(NE / 8 / 256), dim3(256), 0, stream>>>(Opart, Lpart, Opart);
    fc_kernel<<<dim3((2 * S_LEN / 128) * (EMB / 128)), dim3(256), 0, stream>>>(Opart, Wb, bf, Out);
}

// Round 12
// 132.515 us; speedup vs baseline: 1.9760x; 1.3233x over previous
//
#include <hip/hip_runtime.h>
#include <hip/hip_bf16.h>
#include <math.h>

#define S_LEN 2048
#define EMB   1024
#define HEADS 16
#define HDIM  64
#define SPLIT 4
#define NITER ((S_LEN / SPLIT) / 64)   // 8

#define C_SCALE   0.045084439f
#define BIAS_OK  -2.0f

#define NE  ((size_t)2 * S_LEN * EMB)
#define NL  ((size_t)2 * S_LEN * HEADS)
#define NMB ((size_t)2 * S_LEN * S_LEN / 64)

typedef __bf16 bf16x8 __attribute__((ext_vector_type(8)));
typedef float  f32x4  __attribute__((ext_vector_type(4)));
typedef float  f32x16 __attribute__((ext_vector_type(16)));

__device__ __forceinline__ bf16x8 cvt8(const float* v) {
    bf16x8 r;
#pragma unroll
    for (int i = 0; i < 8; ++i) r[i] = (__bf16)v[i];
    return r;
}
__device__ __forceinline__ unsigned long long pack4(float a, float b, float c, float d) {
    __bf16 t[4] = {(__bf16)a, (__bf16)b, (__bf16)c, (__bf16)d};
    return *(unsigned long long*)t;
}
__device__ __forceinline__ bf16x8 cat2(unsigned long long lo, unsigned long long hi) {
    unsigned long long t[2] = {lo, hi};
    return *(bf16x8*)t;
}
__device__ __forceinline__ void gld_lds16(const void* g, void* l) {
    __builtin_amdgcn_global_load_lds(
        (const __attribute__((address_space(1))) void*)g,
        (__attribute__((address_space(3))) void*)l, 16, 0, 0);
}

// ---------------- Pre-pass: cvt W + bit-pack mask (natural k-order) ----------------
__global__ __launch_bounds__(256)
void prepass_kernel(const float* __restrict__ Wf, const int* __restrict__ Mp,
                    __bf16* __restrict__ Wb, unsigned long long* __restrict__ Mb) {
    const int bid = blockIdx.x, tid = threadIdx.x;
    if (bid < 512) {
        size_t i = ((size_t)bid * 256 + tid) * 8;
        float t[8];
        *(float4*)&t[0] = *(const float4*)(Wf + i);
        *(float4*)&t[4] = *(const float4*)(Wf + i + 4);
        *(bf16x8*)(Wb + i) = cvt8(t);
    } else {
        const int w = tid >> 6, lane = tid & 63;
        const int wg = (bid - 512) * 4 + w;
#pragma unroll 4
        for (int it = 0; it < 64; ++it) {
            size_t W = (size_t)wg * 64 + it;
            int v = Mp[W * 64 + lane];
            unsigned long long b = __ballot(v != 0);
            if (lane == 0) Mb[W] = b;
        }
    }
}

// ------- Attention: 32x32 MFMA, in-reg softmax, KV-split, T14 pipelined staging -------
// NOTE launch_bounds(256, 3): VGPR cap ~170. At (256,4) (cap 128) the compiler SPILLED
// the kreg/vreg staging registers to scratch (r11: WRITE_SIZE 242 MB, attn 158us).
// Occupancy is unchanged vs r9 (~3 blocks/CU) since compute already used ~11.5 waves/CU.
__global__ __launch_bounds__(256, 3)
void attn_kernel(const float* __restrict__ Vp, const float* __restrict__ Kp,
                 const float* __restrict__ Qp, const unsigned long long* __restrict__ Mb,
                 __bf16* __restrict__ Opart, float* __restrict__ Lpart) {
    __shared__ __bf16 Klds[2][64 * 64];    // double-buffered, XOR-swizzled, 16KB
    __shared__ __bf16 Vtlds[2][64 * 64];   // double-buffered, XOR-swizzled, 16KB

    const int tid  = threadIdx.x;
    const int lane = tid & 63;
    const int w    = tid >> 6;
    const int nblk = 2 * HEADS * SPLIT * 16;
    const int bid  = (blockIdx.x & 7) * (nblk / 8) + (blockIdx.x >> 3); // XCD chunked swizzle
    const int qt = bid & 15;
    const int sp = (bid >> 4) & (SPLIT - 1);
    const int h  = (bid >> 6) & 15;
    const int n  = bid >> 10;

    const int ql = lane & 31;
    const int g  = lane >> 5;

    const float* qbase = Qp + (size_t)n * S_LEN * EMB + h * HDIM;
    const float* kbase = Kp + (size_t)n * S_LEN * EMB + h * HDIM;
    const float* vbase = Vp + (size_t)n * S_LEN * EMB + h * HDIM;

    const int q = qt * 128 + w * 32 + ql;

    // Q fragments (B operand, 32x32x16)
    bf16x8 qfrag[4];
#pragma unroll
    for (int ds_ = 0; ds_ < 4; ++ds_) {
        const float* qp = qbase + (size_t)q * EMB + ds_ * 16 + g * 8;
        float tmp[8];
        *(float4*)&tmp[0] = *(const float4*)qp;
        *(float4*)&tmp[4] = *(const float4*)(qp + 4);
        qfrag[ds_] = cvt8(tmp);
    }

    f32x16 oacc[2] = {};
    float la = 0.f;

    const unsigned long long* mrow = Mb + ((size_t)(n * S_LEN + q) << 5) + sp * NITER;

    const int sk  = tid >> 2;          // K row 0..63
    const int sdq = (tid & 3) * 16;    // K col base
    const int d0  = (tid & 31) * 2;    // Vt d pair
    const int kv8 = (tid >> 5) * 8;    // Vt kv octet

    const int kvbase = sp * (S_LEN / SPLIT);

    float kreg[16], vreg[16];

#define LOADKV(T) do {                                                                \
        const float* kp_ = kbase + (size_t)(kvbase + (T) * 64 + sk) * EMB + sdq;      \
        *(float4*)&kreg[0]  = *(const float4*)kp_;                                    \
        *(float4*)&kreg[4]  = *(const float4*)(kp_ + 4);                              \
        *(float4*)&kreg[8]  = *(const float4*)(kp_ + 8);                              \
        *(float4*)&kreg[12] = *(const float4*)(kp_ + 12);                             \
        const float* vp_ = vbase + (size_t)(kvbase + (T) * 64 + kv8) * EMB + d0;      \
        _Pragma("unroll")                                                             \
        for (int j = 0; j < 8; ++j)                                                   \
            *(float2*)&vreg[j * 2] = *(const float2*)(vp_ + (size_t)j * EMB);         \
    } while (0)

#define WRITEKV(B) do {                                                               \
        *(bf16x8*)((char*)Klds[B] + sk * 128 + ((sdq * 2)       ^ ((sk & 7) << 4))) = cvt8(&kreg[0]); \
        *(bf16x8*)((char*)Klds[B] + sk * 128 + (((sdq + 8) * 2) ^ ((sk & 7) << 4))) = cvt8(&kreg[8]); \
        float r0_[8], r1_[8];                                                         \
        _Pragma("unroll")                                                             \
        for (int j = 0; j < 8; ++j) { r0_[j] = vreg[2 * j]; r1_[j] = vreg[2 * j + 1]; } \
        *(bf16x8*)((char*)Vtlds[B] + d0 * 128       + ((kv8 * 2) ^ ((d0 & 7) << 4)))       = cvt8(r0_); \
        *(bf16x8*)((char*)Vtlds[B] + (d0 + 1) * 128 + ((kv8 * 2) ^ (((d0 + 1) & 7) << 4))) = cvt8(r1_); \
    } while (0)

    // prologue: tile 0 staged (pays latency once)
    LOADKV(0);
    WRITEKV(0);
    __syncthreads();

#pragma unroll 1
    for (int t = 0; t < NITER; ++t) {
        const int buf = t & 1;
        // issue next tile's global loads FIRST — latency hides under compute below
        if (t < NITER - 1) LOADKV(t + 1);
        const unsigned long long m64 = mrow[t];

#pragma unroll
        for (int kt = 0; kt < 2; ++kt) {
            // QK^T swapped 32x32: E[k_local][q]
            f32x16 E = {};
            __builtin_amdgcn_s_setprio(1);
#pragma unroll
            for (int ds_ = 0; ds_ < 4; ++ds_) {
                int row = kt * 32 + ql;
                bf16x8 kf = *(const bf16x8*)((char*)Klds[buf] + row * 128 +
                    ((ds_ * 32 + g * 16) ^ ((row & 7) << 4)));
                E = __builtin_amdgcn_mfma_f32_32x32x16_bf16(kf, qfrag[ds_], E, 0, 0, 0);
            }
            __builtin_amdgcn_s_setprio(0);

            // in-register softmax: p = exp2(e*C - 2) * maskbit
            const unsigned u = (unsigned)(m64 >> (kt * 32 + 4 * g));
            unsigned long long own[4];
#pragma unroll
            for (int rq = 0; rq < 4; ++rq) {
                unsigned nib = u >> (8 * rq);
                float p0 = __builtin_amdgcn_exp2f(fmaf(E[4*rq+0], C_SCALE, BIAS_OK)) * (float)(nib & 1u);
                float p1 = __builtin_amdgcn_exp2f(fmaf(E[4*rq+1], C_SCALE, BIAS_OK)) * (float)((nib >> 1) & 1u);
                float p2 = __builtin_amdgcn_exp2f(fmaf(E[4*rq+2], C_SCALE, BIAS_OK)) * (float)((nib >> 2) & 1u);
                float p3 = __builtin_amdgcn_exp2f(fmaf(E[4*rq+3], C_SCALE, BIAS_OK)) * (float)((nib >> 3) & 1u);
                la += (p0 + p1) + (p2 + p3);
                own[rq] = pack4(p0, p1, p2, p3);
            }

            // cross-half exchange -> PV B-frags
            unsigned long long sa = g ? own[0] : own[1];
            unsigned long long sb = g ? own[2] : own[3];
            unsigned long long ra = __shfl_xor((long long)sa, 32);
            unsigned long long rb = __shfl_xor((long long)sb, 32);
            bf16x8 frag0 = g ? cat2(ra, own[1]) : cat2(own[0], ra);
            bf16x8 frag1 = g ? cat2(rb, own[3]) : cat2(own[2], rb);

            // PV swapped 32x32
            __builtin_amdgcn_s_setprio(1);
#pragma unroll
            for (int dt = 0; dt < 2; ++dt) {
                int row = dt * 32 + ql;
                bf16x8 v0 = *(const bf16x8*)((char*)Vtlds[buf] + row * 128 +
                    (((2*kt) * 32 + g * 16) ^ ((row & 7) << 4)));
                bf16x8 v1 = *(const bf16x8*)((char*)Vtlds[buf] + row * 128 +
                    (((2*kt+1) * 32 + g * 16) ^ ((row & 7) << 4)));
                oacc[dt] = __builtin_amdgcn_mfma_f32_32x32x16_bf16(v0, frag0, oacc[dt], 0, 0, 0);
                oacc[dt] = __builtin_amdgcn_mfma_f32_32x32x16_bf16(v1, frag1, oacc[dt], 0, 0, 0);
            }
            __builtin_amdgcn_s_setprio(0);
        }

        // write next tile into the OTHER buffer (loads long since returned), then sync
        if (t < NITER - 1) WRITEKV(buf ^ 1);
        __syncthreads();
    }
#undef LOADKV
#undef WRITEKV

    // epilogue: UNNORMALIZED partial O (bf16) + partial l (f32)
    float lt = la + __shfl_xor(la, 32);
    __bf16* op = Opart + (size_t)sp * NE + ((size_t)n * S_LEN + q) * EMB + h * HDIM;
#pragma unroll
    for (int dt = 0; dt < 2; ++dt)
#pragma unroll
        for (int rq = 0; rq < 4; ++rq)
            *(unsigned long long*)(op + dt * 32 + 8 * rq + 4 * g) =
                pack4(oacc[dt][4*rq], oacc[dt][4*rq+1], oacc[dt][4*rq+2], oacc[dt][4*rq+3]);
    if (g == 0)
        Lpart[(size_t)sp * NL + ((size_t)n * S_LEN + q) * HEADS + h] = lt;
}

// ---------------- Reduce: X = (sum_s O_s) / (sum_s l_s); X aliases Opart[0] ----------
__global__ __launch_bounds__(256)
void reduce_kernel(const __bf16* __restrict__ Opart, const float* __restrict__ Lpart,
                   __bf16* __restrict__ X) {
    size_t e0 = ((size_t)blockIdx.x * 256 + threadIdx.x) * 8;
    size_t hr = e0 >> 6;
    float l = 0.f;
#pragma unroll
    for (int s = 0; s < SPLIT; ++s) l += Lpart[s * NL + hr];
    float inv = 1.f / l;
    float acc[8] = {};
#pragma unroll
    for (int s = 0; s < SPLIT; ++s) {
        bf16x8 v = *(const bf16x8*)(Opart + s * NE + e0);
#pragma unroll
        for (int i = 0; i < 8; ++i) acc[i] += (float)v[i];
    }
    bf16x8 r;
#pragma unroll
    for (int i = 0; i < 8; ++i) r[i] = (__bf16)(acc[i] * inv);
    *(bf16x8*)(X + e0) = r;
}

// ---------------- FC kernel: Out = X @ W^T + b (128x128 tile, global_load_lds) -------
__global__ __launch_bounds__(256)
void fc_kernel(const __bf16* __restrict__ X, const __bf16* __restrict__ Wb,
               const float* __restrict__ bfc, float* __restrict__ Out) {
    __shared__ __bf16 Al[128 * 32];
    __shared__ __bf16 Bl[128 * 32];
    const int tid = threadIdx.x, lane = tid & 63, w = tid >> 6;
    const int ql = lane & 15, g = lane >> 4;
    const int bm = blockIdx.x >> 3, bn = blockIdx.x & 7;
    const int wr = w >> 1, wc = w & 1;

    const int rowL = lane >> 2;
    const int colE = (lane & 3) * 8;

    f32x4 acc[4][4] = {};

    for (int k0 = 0; k0 < EMB; k0 += 32) {
        __syncthreads();
        const int q0 = w * 2, q1 = w * 2 + 1;
        gld_lds16(X  + (size_t)(bm * 128 + q0 * 16 + rowL) * EMB + k0 + colE, Al + q0 * 512);
        gld_lds16(X  + (size_t)(bm * 128 + q1 * 16 + rowL) * EMB + k0 + colE, Al + q1 * 512);
        gld_lds16(Wb + (size_t)(bn * 128 + q0 * 16 + rowL) * EMB + k0 + colE, Bl + q0 * 512);
        gld_lds16(Wb + (size_t)(bn * 128 + q1 * 16 + rowL) * EMB + k0 + colE, Bl + q1 * 512);
        __syncthreads();

        bf16x8 a[4], b[4];
#pragma unroll
        for (int mi = 0; mi < 4; ++mi)
            a[mi] = *(const bf16x8*)(Al + (wr * 64 + mi * 16 + ql) * 32 + g * 8);
#pragma unroll
        for (int nj = 0; nj < 4; ++nj)
            b[nj] = *(const bf16x8*)(Bl + (wc * 64 + nj * 16 + ql) * 32 + g * 8);
#pragma unroll
        for (int mi = 0; mi < 4; ++mi)
#pragma unroll
            for (int nj = 0; nj < 4; ++nj)
                acc[mi][nj] = __builtin_amdgcn_mfma_f32_16x16x32_bf16(a[mi], b[nj], acc[mi][nj], 0, 0, 0);
    }

#pragma unroll
    for (int nj = 0; nj < 4; ++nj) {
        int col = bn * 128 + wc * 64 + nj * 16 + ql;
        float bias = bfc[col];
#pragma unroll
        for (int mi = 0; mi < 4; ++mi) {
            int row0 = bm * 128 + wr * 64 + mi * 16 + g * 4;
#pragma unroll
            for (int r = 0; r < 4; ++r)
                Out[(size_t)(row0 + r) * EMB + col] = acc[mi][nj][r] + bias;
        }
    }
}

extern "C" void kernel_launch(void* const* d_in, const int* in_sizes, int n_in,
                              void* d_out, int out_size, void* d_ws, size_t ws_size,
                              hipStream_t stream) {
    const float* Vp = (const float*)d_in[0];
    const float* Kp = (const float*)d_in[1];
    const float* Qp = (const float*)d_in[2];
    const int*   Mp = (const int*)d_in[3];
    const float* Wf = (const float*)d_in[4];
    const float* bf = (const float*)d_in[5];
    float* Out = (float*)d_out;

    char* p = (char*)d_ws;
    __bf16* Opart = (__bf16*)p;             p += SPLIT * NE * 2;        // 32 MB; X aliases Opart[0]
    float*  Lpart = (float*)p;              p += SPLIT * NL * 4;        // 1 MB
    __bf16* Wb    = (__bf16*)p;             p += (size_t)EMB * EMB * 2; // 2 MB
    unsigned long long* Mb = (unsigned long long*)p;                    // 1 MB

    prepass_kernel<<<dim3(1024), dim3(256), 0, stream>>>(Wf, Mp, Wb, Mb);
    attn_kernel<<<dim3(2 * HEADS * SPLIT * 16), dim3(256), 0, stream>>>(Vp, Kp, Qp, Mb, Opart, Lpart);
    reduce_kernel<<<dim3(NE / 8 / 256), dim3(256), 0, stream>>>(Opart, Lpart, Opart);
    fc_kernel<<<dim3((2 * S_LEN / 128) * (EMB / 128)), dim3(256), 0, stream>>>(Opart, Wb, bf, Out);
}

// Round 13
// 132.156 us; speedup vs baseline: 1.9814x; 1.0027x over previous
//
#include <hip/hip_runtime.h>
#include <hip/hip_bf16.h>
#include <math.h>

#define S_LEN 2048
#define EMB   1024
#define HEADS 16
#define HDIM  64
#define SPLIT 4
#define NITER ((S_LEN / SPLIT) / 64)   // 8

#define C_SCALE   0.045084439f
#define BIAS_OK  -2.0f

#define NE  ((size_t)2 * S_LEN * EMB)
#define NL  ((size_t)2 * S_LEN * HEADS)
#define NMB ((size_t)2 * S_LEN * S_LEN / 64)
#define NTILE_ELEMS 4096               // 8 KB bf16 tile image

typedef __bf16 bf16x8 __attribute__((ext_vector_type(8)));
typedef float  f32x4  __attribute__((ext_vector_type(4)));
typedef float  f32x16 __attribute__((ext_vector_type(16)));

__device__ __forceinline__ bf16x8 cvt8(const float* v) {
    bf16x8 r;
#pragma unroll
    for (int i = 0; i < 8; ++i) r[i] = (__bf16)v[i];
    return r;
}
__device__ __forceinline__ unsigned long long pack4(float a, float b, float c, float d) {
    __bf16 t[4] = {(__bf16)a, (__bf16)b, (__bf16)c, (__bf16)d};
    return *(unsigned long long*)t;
}
__device__ __forceinline__ bf16x8 cat2(unsigned long long lo, unsigned long long hi) {
    unsigned long long t[2] = {lo, hi};
    return *(bf16x8*)t;
}
__device__ __forceinline__ void gld_lds16(const void* g, void* l) {
    __builtin_amdgcn_global_load_lds(
        (const __attribute__((address_space(1))) void*)g,
        (__attribute__((address_space(3))) void*)l, 16, 0, 0);
}

// ---------------- Pre-pass ----------------
// bid [0,1024): K swizzled tile images      [1024,2048): V transposed+swizzled images
//     [2048,4096): Q f32->bf16              [4096,4608): W cvt    [4608,5120): mask pack
// Tile image byte (r*128 + ((c) ^ ((r&7)<<4))) = elem[r][c/2] — identical to what r12's
// WRITEKV produced in LDS, so attn can global_load_lds the image LINEARLY (m104/rule 21).
__global__ __launch_bounds__(256)
void prepass_kernel(const float* __restrict__ Kp, const float* __restrict__ Vp,
                    const float* __restrict__ Qp, const float* __restrict__ Wf,
                    const int* __restrict__ Mp,
                    __bf16* __restrict__ Kb, __bf16* __restrict__ Vtb,
                    __bf16* __restrict__ Qb, __bf16* __restrict__ Wb,
                    unsigned long long* __restrict__ Mb) {
    __shared__ __bf16 Lp[64 * 72];   // V transpose staging (stride 72 elems = 144 B)
    const int bid = blockIdx.x, tid = threadIdx.x;

    if (bid < 1024) {
        // ---- K tile image: rows r = kv (swizzled within row) ----
        const int tile = bid;
        const int n = tile >> 9, h = (tile >> 5) & 15, kvt = tile & 31;
        const int r = tid >> 2, d0 = (tid & 3) * 16;
        const float* src = Kp + ((size_t)n * S_LEN + kvt * 64 + r) * EMB + h * 64 + d0;
        float t[16];
        *(float4*)&t[0]  = *(const float4*)src;
        *(float4*)&t[4]  = *(const float4*)(src + 4);
        *(float4*)&t[8]  = *(const float4*)(src + 8);
        *(float4*)&t[12] = *(const float4*)(src + 12);
        char* img = (char*)(Kb + (size_t)tile * NTILE_ELEMS);
        *(bf16x8*)(img + r * 128 + ((d0 * 2)       ^ ((r & 7) << 4))) = cvt8(&t[0]);
        *(bf16x8*)(img + r * 128 + (((d0 + 8) * 2) ^ ((r & 7) << 4))) = cvt8(&t[8]);
    } else if (bid < 2048) {
        // ---- V^T tile image: rows r = d (transposed via LDS, swizzled within row) ----
        const int tile = bid - 1024;
        const int n = tile >> 9, h = (tile >> 5) & 15, kvt = tile & 31;
        {
            const int kv = tid >> 2, d0 = (tid & 3) * 16;
            const float* src = Vp + ((size_t)n * S_LEN + kvt * 64 + kv) * EMB + h * 64 + d0;
            float t[16];
            *(float4*)&t[0]  = *(const float4*)src;
            *(float4*)&t[4]  = *(const float4*)(src + 4);
            *(float4*)&t[8]  = *(const float4*)(src + 8);
            *(float4*)&t[12] = *(const float4*)(src + 12);
            *(bf16x8*)&Lp[kv * 72 + d0]     = cvt8(&t[0]);
            *(bf16x8*)&Lp[kv * 72 + d0 + 8] = cvt8(&t[8]);
        }
        __syncthreads();
        {
            const int d = tid >> 2, kvg = (tid & 3) * 16;
            __bf16 a[16];
#pragma unroll
            for (int j = 0; j < 16; ++j) a[j] = Lp[(kvg + j) * 72 + d];
            char* img = (char*)(Vtb + (size_t)tile * NTILE_ELEMS);
            *(bf16x8*)(img + d * 128 + ((kvg * 2)        ^ ((d & 7) << 4))) = *(bf16x8*)&a[0];
            *(bf16x8*)(img + d * 128 + (((kvg + 16) * 2 - 16) ^ ((d & 7) << 4))) = *(bf16x8*)&a[8];
        }
    } else if (bid < 4096) {
        size_t i = (((size_t)(bid - 2048)) * 256 + tid) * 8;
        float t[8];
        *(float4*)&t[0] = *(const float4*)(Qp + i);
        *(float4*)&t[4] = *(const float4*)(Qp + i + 4);
        *(bf16x8*)(Qb + i) = cvt8(t);
    } else if (bid < 4608) {
        size_t i = (((size_t)(bid - 4096)) * 256 + tid) * 8;
        float t[8];
        *(float4*)&t[0] = *(const float4*)(Wf + i);
        *(float4*)&t[4] = *(const float4*)(Wf + i + 4);
        *(bf16x8*)(Wb + i) = cvt8(t);
    } else {
        const int w = tid >> 6, lane = tid & 63;
        const int wg = (bid - 4608) * 4 + w;
#pragma unroll 4
        for (int it = 0; it < 64; ++it) {
            size_t W = (size_t)wg * 64 + it;
            int v = Mp[W * 64 + lane];
            unsigned long long b = __ballot(v != 0);
            if (lane == 0) Mb[W] = b;
        }
    }
}

// --- Attention: 32x32 MFMA, in-reg softmax, KV-split, async gload_lds 2-phase pipe ---
__global__ __launch_bounds__(256, 4)
void attn_kernel(const __bf16* __restrict__ Vtb, const __bf16* __restrict__ Kb,
                 const __bf16* __restrict__ Qb, const unsigned long long* __restrict__ Mb,
                 __bf16* __restrict__ Opart, float* __restrict__ Lpart) {
    __shared__ __bf16 Klds[2][64 * 64];    // double-buffered pre-swizzled images, 16KB
    __shared__ __bf16 Vtlds[2][64 * 64];   // double-buffered pre-swizzled images, 16KB

    const int tid  = threadIdx.x;
    const int lane = tid & 63;
    const int w    = tid >> 6;
    const int nblk = 2 * HEADS * SPLIT * 16;
    const int bid  = (blockIdx.x & 7) * (nblk / 8) + (blockIdx.x >> 3); // XCD chunked swizzle
    const int qt = bid & 15;
    const int sp = (bid >> 4) & (SPLIT - 1);
    const int h  = (bid >> 6) & 15;
    const int n  = bid >> 10;

    const int ql = lane & 31;
    const int g  = lane >> 5;

    const int q = qt * 128 + w * 32 + ql;

    // Q fragments (B operand, 32x32x16) — bf16 direct
    bf16x8 qfrag[4];
#pragma unroll
    for (int ds_ = 0; ds_ < 4; ++ds_) {
        qfrag[ds_] = *(const bf16x8*)(Qb + ((size_t)n * S_LEN + q) * EMB + h * 64 + ds_ * 16 + g * 8);
    }

    f32x16 oacc[2] = {};
    float la = 0.f;

    const unsigned long long* mrow = Mb + ((size_t)(n * S_LEN + q) << 5) + sp * NITER;

    const __bf16* ktiles = Kb  + ((size_t)((n * 16 + h) * 32) + sp * 8) * NTILE_ELEMS;
    const __bf16* vtiles = Vtb + ((size_t)((n * 16 + h) * 32) + sp * 8) * NTILE_ELEMS;

    // async staging: 4 x global_load_lds (16B/lane), no VGPR round-trip, compiler
    // cannot sink it (fire-and-forget); __syncthreads' vmcnt(0) is the wait.
#define STAGE(B, T) do {                                                              \
        const __bf16* kt_ = ktiles + (size_t)(T) * NTILE_ELEMS;                       \
        const __bf16* vt_ = vtiles + (size_t)(T) * NTILE_ELEMS;                       \
        __bf16* kl_ = Klds[B]  + w * 512;                                             \
        __bf16* vl_ = Vtlds[B] + w * 512;                                             \
        gld_lds16(kt_ + w * 512 + lane * 8,        kl_);                              \
        gld_lds16(kt_ + 2048 + w * 512 + lane * 8, kl_ + 2048);                       \
        gld_lds16(vt_ + w * 512 + lane * 8,        vl_);                              \
        gld_lds16(vt_ + 2048 + w * 512 + lane * 8, vl_ + 2048);                       \
    } while (0)

    STAGE(0, 0);
    __syncthreads();

#pragma unroll 1
    for (int t = 0; t < NITER; ++t) {
        const int buf = t & 1;
        if (t < NITER - 1) STAGE(buf ^ 1, t + 1);   // async next-tile loads in flight
        const unsigned long long m64 = mrow[t];

#pragma unroll
        for (int kt = 0; kt < 2; ++kt) {
            // QK^T swapped 32x32: E[k_local][q]
            f32x16 E = {};
            __builtin_amdgcn_s_setprio(1);
#pragma unroll
            for (int ds_ = 0; ds_ < 4; ++ds_) {
                int row = kt * 32 + ql;
                bf16x8 kf = *(const bf16x8*)((char*)Klds[buf] + row * 128 +
                    ((ds_ * 32 + g * 16) ^ ((row & 7) << 4)));
                E = __builtin_amdgcn_mfma_f32_32x32x16_bf16(kf, qfrag[ds_], E, 0, 0, 0);
            }
            __builtin_amdgcn_s_setprio(0);

            // in-register softmax: p = exp2(e*C - 2) * maskbit
            const unsigned u = (unsigned)(m64 >> (kt * 32 + 4 * g));
            unsigned long long own[4];
#pragma unroll
            for (int rq = 0; rq < 4; ++rq) {
                unsigned nib = u >> (8 * rq);
                float p0 = __builtin_amdgcn_exp2f(fmaf(E[4*rq+0], C_SCALE, BIAS_OK)) * (float)(nib & 1u);
                float p1 = __builtin_amdgcn_exp2f(fmaf(E[4*rq+1], C_SCALE, BIAS_OK)) * (float)((nib >> 1) & 1u);
                float p2 = __builtin_amdgcn_exp2f(fmaf(E[4*rq+2], C_SCALE, BIAS_OK)) * (float)((nib >> 2) & 1u);
                float p3 = __builtin_amdgcn_exp2f(fmaf(E[4*rq+3], C_SCALE, BIAS_OK)) * (float)((nib >> 3) & 1u);
                la += (p0 + p1) + (p2 + p3);
                own[rq] = pack4(p0, p1, p2, p3);
            }

            // cross-half exchange -> PV B-frags
            unsigned long long sa = g ? own[0] : own[1];
            unsigned long long sb = g ? own[2] : own[3];
            unsigned long long ra = __shfl_xor((long long)sa, 32);
            unsigned long long rb = __shfl_xor((long long)sb, 32);
            bf16x8 frag0 = g ? cat2(ra, own[1]) : cat2(own[0], ra);
            bf16x8 frag1 = g ? cat2(rb, own[3]) : cat2(own[2], rb);

            // PV swapped 32x32
            __builtin_amdgcn_s_setprio(1);
#pragma unroll
            for (int dt = 0; dt < 2; ++dt) {
                int row = dt * 32 + ql;
                bf16x8 v0 = *(const bf16x8*)((char*)Vtlds[buf] + row * 128 +
                    (((2*kt) * 32 + g * 16) ^ ((row & 7) << 4)));
                bf16x8 v1 = *(const bf16x8*)((char*)Vtlds[buf] + row * 128 +
                    (((2*kt+1) * 32 + g * 16) ^ ((row & 7) << 4)));
                oacc[dt] = __builtin_amdgcn_mfma_f32_32x32x16_bf16(v0, frag0, oacc[dt], 0, 0, 0);
                oacc[dt] = __builtin_amdgcn_mfma_f32_32x32x16_bf16(v1, frag1, oacc[dt], 0, 0, 0);
            }
            __builtin_amdgcn_s_setprio(0);
        }

        __syncthreads();   // implicit vmcnt(0): next tile's async loads have landed
    }
#undef STAGE

    // epilogue: UNNORMALIZED partial O (bf16) + partial l (f32)
    float lt = la + __shfl_xor(la, 32);
    __bf16* op = Opart + (size_t)sp * NE + ((size_t)n * S_LEN + q) * EMB + h * HDIM;
#pragma unroll
    for (int dt = 0; dt < 2; ++dt)
#pragma unroll
        for (int rq = 0; rq < 4; ++rq)
            *(unsigned long long*)(op + dt * 32 + 8 * rq + 4 * g) =
                pack4(oacc[dt][4*rq], oacc[dt][4*rq+1], oacc[dt][4*rq+2], oacc[dt][4*rq+3]);
    if (g == 0)
        Lpart[(size_t)sp * NL + ((size_t)n * S_LEN + q) * HEADS + h] = lt;
}

// ---------------- Reduce: X = (sum_s O_s) / (sum_s l_s); X aliases Opart[0] ----------
__global__ __launch_bounds__(256)
void reduce_kernel(const __bf16* __restrict__ Opart, const float* __restrict__ Lpart,
                   __bf16* __restrict__ X) {
    size_t e0 = ((size_t)blockIdx.x * 256 + threadIdx.x) * 8;
    size_t hr = e0 >> 6;
    float l = 0.f;
#pragma unroll
    for (int s = 0; s < SPLIT; ++s) l += Lpart[s * NL + hr];
    float inv = 1.f / l;
    float acc[8] = {};
#pragma unroll
    for (int s = 0; s < SPLIT; ++s) {
        bf16x8 v = *(const bf16x8*)(Opart + s * NE + e0);
#pragma unroll
        for (int i = 0; i < 8; ++i) acc[i] += (float)v[i];
    }
    bf16x8 r;
#pragma unroll
    for (int i = 0; i < 8; ++i) r[i] = (__bf16)(acc[i] * inv);
    *(bf16x8*)(X + e0) = r;
}

// ---------------- FC kernel: Out = X @ W^T + b (128x128 tile, global_load_lds) -------
__global__ __launch_bounds__(256)
void fc_kernel(const __bf16* __restrict__ X, const __bf16* __restrict__ Wb,
               const float* __restrict__ bfc, float* __restrict__ Out) {
    __shared__ __bf16 Al[128 * 32];
    __shared__ __bf16 Bl[128 * 32];
    const int tid = threadIdx.x, lane = tid & 63, w = tid >> 6;
    const int ql = lane & 15, g = lane >> 4;
    const int bm = blockIdx.x >> 3, bn = blockIdx.x & 7;
    const int wr = w >> 1, wc = w & 1;

    const int rowL = lane >> 2;
    const int colE = (lane & 3) * 8;

    f32x4 acc[4][4] = {};

    for (int k0 = 0; k0 < EMB; k0 += 32) {
        __syncthreads();
        const int q0 = w * 2, q1 = w * 2 + 1;
        gld_lds16(X  + (size_t)(bm * 128 + q0 * 16 + rowL) * EMB + k0 + colE, Al + q0 * 512);
        gld_lds16(X  + (size_t)(bm * 128 + q1 * 16 + rowL) * EMB + k0 + colE, Al + q1 * 512);
        gld_lds16(Wb + (size_t)(bn * 128 + q0 * 16 + rowL) * EMB + k0 + colE, Bl + q0 * 512);
        gld_lds16(Wb + (size_t)(bn * 128 + q1 * 16 + rowL) * EMB + k0 + colE, Bl + q1 * 512);
        __syncthreads();

        bf16x8 a[4], b[4];
#pragma unroll
        for (int mi = 0; mi < 4; ++mi)
            a[mi] = *(const bf16x8*)(Al + (wr * 64 + mi * 16 + ql) * 32 + g * 8);
#pragma unroll
        for (int nj = 0; nj < 4; ++nj)
            b[nj] = *(const bf16x8*)(Bl + (wc * 64 + nj * 16 + ql) * 32 + g * 8);
#pragma unroll
        for (int mi = 0; mi < 4; ++mi)
#pragma unroll
            for (int nj = 0; nj < 4; ++nj)
                acc[mi][nj] = __builtin_amdgcn_mfma_f32_16x16x32_bf16(a[mi], b[nj], acc[mi][nj], 0, 0, 0);
    }

#pragma unroll
    for (int nj = 0; nj < 4; ++nj) {
        int col = bn * 128 + wc * 64 + nj * 16 + ql;
        float bias = bfc[col];
#pragma unroll
        for (int mi = 0; mi < 4; ++mi) {
            int row0 = bm * 128 + wr * 64 + mi * 16 + g * 4;
#pragma unroll
            for (int r = 0; r < 4; ++r)
                Out[(size_t)(row0 + r) * EMB + col] = acc[mi][nj][r] + bias;
        }
    }
}

extern "C" void kernel_launch(void* const* d_in, const int* in_sizes, int n_in,
                              void* d_out, int out_size, void* d_ws, size_t ws_size,
                              hipStream_t stream) {
    const float* Vp = (const float*)d_in[0];
    const float* Kp = (const float*)d_in[1];
    const float* Qp = (const float*)d_in[2];
    const int*   Mp = (const int*)d_in[3];
    const float* Wf = (const float*)d_in[4];
    const float* bf = (const float*)d_in[5];
    float* Out = (float*)d_out;

    char* p = (char*)d_ws;
    __bf16* Opart = (__bf16*)p;             p += SPLIT * NE * 2;        // 32 MB; X aliases Opart[0]
    float*  Lpart = (float*)p;              p += SPLIT * NL * 4;        // 1 MB
    __bf16* Wb    = (__bf16*)p;             p += (size_t)EMB * EMB * 2; // 2 MB
    unsigned long long* Mb = (unsigned long long*)p; p += NMB * 8;      // 1 MB
    __bf16* Kb    = (__bf16*)p;             p += (size_t)1024 * NTILE_ELEMS * 2; // 8 MB
    __bf16* Vtb   = (__bf16*)p;             p += (size_t)1024 * NTILE_ELEMS * 2; // 8 MB
    __bf16* Qb    = (__bf16*)p;                                         // 8 MB

    prepass_kernel<<<dim3(5120), dim3(256), 0, stream>>>(Kp, Vp, Qp, Wf, Mp, Kb, Vtb, Qb, Wb, Mb);
    attn_kernel<<<dim3(2 * HEADS * SPLIT * 16), dim3(256), 0, stream>>>(Vtb, Kb, Qb, Mb, Opart, Lpart);
    reduce_kernel<<<dim3(NE / 8 / 256), dim3(256), 0, stream>>>(Opart, Lpart, Opart);
    fc_kernel<<<dim3((2 * S_LEN / 128) * (EMB / 128)), dim3(256), 0, stream>>>(Opart, Wb, bf, Out);
}

// Round 15
// 126.551 us; speedup vs baseline: 2.0691x; 1.0443x over previous
//
#include <hip/hip_runtime.h>
#include <hip/hip_bf16.h>
#include <math.h>

#define S_LEN 2048
#define EMB   1024
#define HEADS 16
#define HDIM  64
#define SPLIT 2
#define NITER ((S_LEN / SPLIT) / 64)   // 16

#define C_SCALE   0.045084439f
#define BIAS_OK  -2.0f

#define NE  ((size_t)2 * S_LEN * EMB)
#define NL  ((size_t)2 * S_LEN * HEADS)
#define NMB ((size_t)2 * S_LEN * S_LEN / 64)
#define NTILE_ELEMS 4096               // 8 KB bf16 tile image

typedef __bf16 bf16x8 __attribute__((ext_vector_type(8)));
typedef float  f32x4  __attribute__((ext_vector_type(4)));
typedef float  f32x16 __attribute__((ext_vector_type(16)));

__device__ __forceinline__ bf16x8 cvt8(const float* v) {
    bf16x8 r;
#pragma unroll
    for (int i = 0; i < 8; ++i) r[i] = (__bf16)v[i];
    return r;
}
__device__ __forceinline__ unsigned long long pack4(float a, float b, float c, float d) {
    __bf16 t[4] = {(__bf16)a, (__bf16)b, (__bf16)c, (__bf16)d};
    return *(unsigned long long*)t;
}
__device__ __forceinline__ bf16x8 cat2(unsigned long long lo, unsigned long long hi) {
    unsigned long long t[2] = {lo, hi};
    return *(bf16x8*)t;
}
__device__ __forceinline__ void gld_lds16(const void* g, void* l) {
    __builtin_amdgcn_global_load_lds(
        (const __attribute__((address_space(1))) void*)g,
        (__attribute__((address_space(3))) void*)l, 16, 0, 0);
}

// ---------------- Pre-pass ----------------
// bid [0,1024): K swizzled tile images   [1024,2048): V transposed+swizzled images
//     [2048,2560): W cvt                 [2560,3072): mask pack
__global__ __launch_bounds__(256)
void prepass_kernel(const float* __restrict__ Kp, const float* __restrict__ Vp,
                    const float* __restrict__ Wf, const int* __restrict__ Mp,
                    __bf16* __restrict__ Kb, __bf16* __restrict__ Vtb,
                    __bf16* __restrict__ Wb, unsigned long long* __restrict__ Mb) {
    __shared__ __bf16 Lp[64 * 72];
    const int bid = blockIdx.x, tid = threadIdx.x;

    if (bid < 1024) {
        const int tile = bid;
        const int n = tile >> 9, h = (tile >> 5) & 15, kvt = tile & 31;
        const int r = tid >> 2, d0 = (tid & 3) * 16;
        const float* src = Kp + ((size_t)n * S_LEN + kvt * 64 + r) * EMB + h * 64 + d0;
        float t[16];
        *(float4*)&t[0]  = *(const float4*)src;
        *(float4*)&t[4]  = *(const float4*)(src + 4);
        *(float4*)&t[8]  = *(const float4*)(src + 8);
        *(float4*)&t[12] = *(const float4*)(src + 12);
        char* img = (char*)(Kb + (size_t)tile * NTILE_ELEMS);
        *(bf16x8*)(img + r * 128 + ((d0 * 2)       ^ ((r & 7) << 4))) = cvt8(&t[0]);
        *(bf16x8*)(img + r * 128 + (((d0 + 8) * 2) ^ ((r & 7) << 4))) = cvt8(&t[8]);
    } else if (bid < 2048) {
        const int tile = bid - 1024;
        const int n = tile >> 9, h = (tile >> 5) & 15, kvt = tile & 31;
        {
            const int kv = tid >> 2, d0 = (tid & 3) * 16;
            const float* src = Vp + ((size_t)n * S_LEN + kvt * 64 + kv) * EMB + h * 64 + d0;
            float t[16];
            *(float4*)&t[0]  = *(const float4*)src;
            *(float4*)&t[4]  = *(const float4*)(src + 4);
            *(float4*)&t[8]  = *(const float4*)(src + 8);
            *(float4*)&t[12] = *(const float4*)(src + 12);
            *(bf16x8*)&Lp[kv * 72 + d0]     = cvt8(&t[0]);
            *(bf16x8*)&Lp[kv * 72 + d0 + 8] = cvt8(&t[8]);
        }
        __syncthreads();
        {
            const int d = tid >> 2, kvg = (tid & 3) * 16;
            __bf16 a[16];
#pragma unroll
            for (int j = 0; j < 16; ++j) a[j] = Lp[(kvg + j) * 72 + d];
            char* img = (char*)(Vtb + (size_t)tile * NTILE_ELEMS);
            *(bf16x8*)(img + d * 128 + ((kvg * 2)        ^ ((d & 7) << 4))) = *(bf16x8*)&a[0];
            *(bf16x8*)(img + d * 128 + (((kvg + 16) * 2 - 16) ^ ((d & 7) << 4))) = *(bf16x8*)&a[8];
        }
    } else if (bid < 2560) {
        size_t i = (((size_t)(bid - 2048)) * 256 + tid) * 8;
        float t[8];
        *(float4*)&t[0] = *(const float4*)(Wf + i);
        *(float4*)&t[4] = *(const float4*)(Wf + i + 4);
        *(bf16x8*)(Wb + i) = cvt8(t);
    } else {
        const int w = tid >> 6, lane = tid & 63;
        const int wg = (bid - 2560) * 4 + w;
#pragma unroll 4
        for (int it = 0; it < 64; ++it) {
            size_t W = (size_t)wg * 64 + it;
            int v = Mp[W * 64 + lane];
            unsigned long long b = __ballot(v != 0);
            if (lane == 0) Mb[W] = b;
        }
    }
}

// --- Attention: 32x32 MFMA, in-reg softmax (shfl exchange, MFMA l-sum), async pipe ---
__global__ __launch_bounds__(256, 4)
void attn_kernel(const __bf16* __restrict__ Vtb, const __bf16* __restrict__ Kb,
                 const float* __restrict__ Qp, const unsigned long long* __restrict__ Mb,
                 __bf16* __restrict__ Opart, float* __restrict__ Lpart) {
    __shared__ __bf16 Klds[2][64 * 64];
    __shared__ __bf16 Vtlds[2][64 * 64];

    const int tid  = threadIdx.x;
    const int lane = tid & 63;
    const int w    = tid >> 6;
    const int nblk = 2 * HEADS * SPLIT * 16;
    const int bid  = (blockIdx.x & 7) * (nblk / 8) + (blockIdx.x >> 3); // XCD chunked swizzle
    const int qt = bid & 15;
    const int sp = (bid >> 4) & (SPLIT - 1);
    const int h  = (bid >> 5) & 15;
    const int n  = bid >> 9;

    const int ql = lane & 31;
    const int g  = lane >> 5;

    const int q = qt * 128 + w * 32 + ql;

    // Q fragments (B operand): f32 direct read + in-reg cvt (once per block)
    bf16x8 qfrag[4];
#pragma unroll
    for (int ds_ = 0; ds_ < 4; ++ds_) {
        const float* qp = Qp + ((size_t)n * S_LEN + q) * EMB + h * HDIM + ds_ * 16 + g * 8;
        float tmp[8];
        *(float4*)&tmp[0] = *(const float4*)qp;
        *(float4*)&tmp[4] = *(const float4*)(qp + 4);
        qfrag[ds_] = cvt8(tmp);
    }

    f32x16 oacc[2] = {};
    f32x16 lacc = {};
    bf16x8 aon;
#pragma unroll
    for (int i = 0; i < 8; ++i) aon[i] = (__bf16)1.0f;

    const unsigned long long* mrow = Mb + ((size_t)(n * S_LEN + q) << 5) + sp * NITER;

    const __bf16* ktiles = Kb  + ((size_t)((n * 16 + h) * 32) + sp * NITER) * NTILE_ELEMS;
    const __bf16* vtiles = Vtb + ((size_t)((n * 16 + h) * 32) + sp * NITER) * NTILE_ELEMS;

#define STAGE(B, T) do {                                                              \
        const __bf16* kt_ = ktiles + (size_t)(T) * NTILE_ELEMS;                       \
        const __bf16* vt_ = vtiles + (size_t)(T) * NTILE_ELEMS;                       \
        __bf16* kl_ = Klds[B]  + w * 512;                                             \
        __bf16* vl_ = Vtlds[B] + w * 512;                                             \
        gld_lds16(kt_ + w * 512 + lane * 8,        kl_);                              \
        gld_lds16(kt_ + 2048 + w * 512 + lane * 8, kl_ + 2048);                       \
        gld_lds16(vt_ + w * 512 + lane * 8,        vl_);                              \
        gld_lds16(vt_ + 2048 + w * 512 + lane * 8, vl_ + 2048);                       \
    } while (0)

    STAGE(0, 0);
    __syncthreads();

#pragma unroll 1
    for (int t = 0; t < NITER; ++t) {
        const int buf = t & 1;
        if (t < NITER - 1) STAGE(buf ^ 1, t + 1);
        const unsigned long long m64 = mrow[t];

#pragma unroll
        for (int kt = 0; kt < 2; ++kt) {
            // QK^T swapped 32x32: E[k_local][q]
            f32x16 E = {};
            __builtin_amdgcn_s_setprio(1);
#pragma unroll
            for (int ds_ = 0; ds_ < 4; ++ds_) {
                int row = kt * 32 + ql;
                bf16x8 kf = *(const bf16x8*)((char*)Klds[buf] + row * 128 +
                    ((ds_ * 32 + g * 16) ^ ((row & 7) << 4)));
                E = __builtin_amdgcn_mfma_f32_32x32x16_bf16(kf, qfrag[ds_], E, 0, 0, 0);
            }
            __builtin_amdgcn_s_setprio(0);

            // in-register softmax: p = exp2(e*C - 2) * maskbit
            const unsigned u = (unsigned)(m64 >> (kt * 32 + 4 * g));
            unsigned long long own[4];
#pragma unroll
            for (int rq = 0; rq < 4; ++rq) {
                unsigned nib = u >> (8 * rq);
                float p0 = __builtin_amdgcn_exp2f(fmaf(E[4*rq+0], C_SCALE, BIAS_OK)) * (float)(nib & 1u);
                float p1 = __builtin_amdgcn_exp2f(fmaf(E[4*rq+1], C_SCALE, BIAS_OK)) * (float)((nib >> 1) & 1u);
                float p2 = __builtin_amdgcn_exp2f(fmaf(E[4*rq+2], C_SCALE, BIAS_OK)) * (float)((nib >> 2) & 1u);
                float p3 = __builtin_amdgcn_exp2f(fmaf(E[4*rq+3], C_SCALE, BIAS_OK)) * (float)((nib >> 3) & 1u);
                own[rq] = pack4(p0, p1, p2, p3);
            }

            // cross-half exchange -> PV B-frags (r13-verified shfl form)
            unsigned long long sa = g ? own[0] : own[1];
            unsigned long long sb = g ? own[2] : own[3];
            unsigned long long ra = __shfl_xor((long long)sa, 32);
            unsigned long long rb = __shfl_xor((long long)sb, 32);
            bf16x8 frag0 = g ? cat2(ra, own[1]) : cat2(own[0], ra);
            bf16x8 frag1 = g ? cat2(rb, own[3]) : cat2(own[2], rb);

            // PV swapped 32x32 + l-sum via ones-MFMA (every lane gets full row sum)
            __builtin_amdgcn_s_setprio(1);
            lacc = __builtin_amdgcn_mfma_f32_32x32x16_bf16(aon, frag0, lacc, 0, 0, 0);
            lacc = __builtin_amdgcn_mfma_f32_32x32x16_bf16(aon, frag1, lacc, 0, 0, 0);
#pragma unroll
            for (int dt = 0; dt < 2; ++dt) {
                int row = dt * 32 + ql;
                bf16x8 v0 = *(const bf16x8*)((char*)Vtlds[buf] + row * 128 +
                    (((2*kt) * 32 + g * 16) ^ ((row & 7) << 4)));
                bf16x8 v1 = *(const bf16x8*)((char*)Vtlds[buf] + row * 128 +
                    (((2*kt+1) * 32 + g * 16) ^ ((row & 7) << 4)));
                oacc[dt] = __builtin_amdgcn_mfma_f32_32x32x16_bf16(v0, frag0, oacc[dt], 0, 0, 0);
                oacc[dt] = __builtin_amdgcn_mfma_f32_32x32x16_bf16(v1, frag1, oacc[dt], 0, 0, 0);
            }
            __builtin_amdgcn_s_setprio(0);
        }

        __syncthreads();   // implicit vmcnt(0): next tile's async loads have landed
    }
#undef STAGE

    // epilogue: UNNORMALIZED partial O (bf16) + partial l (f32; lacc[0] = full sum)
    __bf16* op = Opart + (size_t)sp * NE + ((size_t)n * S_LEN + q) * EMB + h * HDIM;
#pragma unroll
    for (int dt = 0; dt < 2; ++dt)
#pragma unroll
        for (int rq = 0; rq < 4; ++rq)
            *(unsigned long long*)(op + dt * 32 + 8 * rq + 4 * g) =
                pack4(oacc[dt][4*rq], oacc[dt][4*rq+1], oacc[dt][4*rq+2], oacc[dt][4*rq+3]);
    if (g == 0)
        Lpart[(size_t)sp * NL + ((size_t)n * S_LEN + q) * HEADS + h] = lacc[0];
}

// ---------------- Reduce: X = (sum_s O_s) / (sum_s l_s); X aliases Opart[0] ----------
__global__ __launch_bounds__(256)
void reduce_kernel(const __bf16* __restrict__ Opart, const float* __restrict__ Lpart,
                   __bf16* __restrict__ X) {
    size_t e0 = ((size_t)blockIdx.x * 256 + threadIdx.x) * 8;
    size_t hr = e0 >> 6;
    float l = 0.f;
#pragma unroll
    for (int s = 0; s < SPLIT; ++s) l += Lpart[s * NL + hr];
    float inv = 1.f / l;
    float acc[8] = {};
#pragma unroll
    for (int s = 0; s < SPLIT; ++s) {
        bf16x8 v = *(const bf16x8*)(Opart + s * NE + e0);
#pragma unroll
        for (int i = 0; i < 8; ++i) acc[i] += (float)v[i];
    }
    bf16x8 r;
#pragma unroll
    for (int i = 0; i < 8; ++i) r[i] = (__bf16)(acc[i] * inv);
    *(bf16x8*)(X + e0) = r;
}

// ---------------- FC kernel: Out = X @ W^T + b (128x128 tile, global_load_lds) -------
__global__ __launch_bounds__(256)
void fc_kernel(const __bf16* __restrict__ X, const __bf16* __restrict__ Wb,
               const float* __restrict__ bfc, float* __restrict__ Out) {
    __shared__ __bf16 Al[128 * 32];
    __shared__ __bf16 Bl[128 * 32];
    const int tid = threadIdx.x, lane = tid & 63, w = tid >> 6;
    const int ql = lane & 15, g = lane >> 4;
    const int bm = blockIdx.x >> 3, bn = blockIdx.x & 7;
    const int wr = w >> 1, wc = w & 1;

    const int rowL = lane >> 2;
    const int colE = (lane & 3) * 8;

    f32x4 acc[4][4] = {};

    for (int k0 = 0; k0 < EMB; k0 += 32) {
        __syncthreads();
        const int q0 = w * 2, q1 = w * 2 + 1;
        gld_lds16(X  + (size_t)(bm * 128 + q0 * 16 + rowL) * EMB + k0 + colE, Al + q0 * 512);
        gld_lds16(X  + (size_t)(bm * 128 + q1 * 16 + rowL) * EMB + k0 + colE, Al + q1 * 512);
        gld_lds16(Wb + (size_t)(bn * 128 + q0 * 16 + rowL) * EMB + k0 + colE, Bl + q0 * 512);
        gld_lds16(Wb + (size_t)(bn * 128 + q1 * 16 + rowL) * EMB + k0 + colE, Bl + q1 * 512);
        __syncthreads();

        bf16x8 a[4], b[4];
#pragma unroll
        for (int mi = 0; mi < 4; ++mi)
            a[mi] = *(const bf16x8*)(Al + (wr * 64 + mi * 16 + ql) * 32 + g * 8);
#pragma unroll
        for (int nj = 0; nj < 4; ++nj)
            b[nj] = *(const bf16x8*)(Bl + (wc * 64 + nj * 16 + ql) * 32 + g * 8);
#pragma unroll
        for (int mi = 0; mi < 4; ++mi)
#pragma unroll
            for (int nj = 0; nj < 4; ++nj)
                acc[mi][nj] = __builtin_amdgcn_mfma_f32_16x16x32_bf16(a[mi], b[nj], acc[mi][nj], 0, 0, 0);
    }

#pragma unroll
    for (int nj = 0; nj < 4; ++nj) {
        int col = bn * 128 + wc * 64 + nj * 16 + ql;
        float bias = bfc[col];
#pragma unroll
        for (int mi = 0; mi < 4; ++mi) {
            int row0 = bm * 128 + wr * 64 + mi * 16 + g * 4;
#pragma unroll
            for (int r = 0; r < 4; ++r)
                Out[(size_t)(row0 + r) * EMB + col] = acc[mi][nj][r] + bias;
        }
    }
}

extern "C" void kernel_launch(void* const* d_in, const int* in_sizes, int n_in,
                              void* d_out, int out_size, void* d_ws, size_t ws_size,
                              hipStream_t stream) {
    const float* Vp = (const float*)d_in[0];
    const float* Kp = (const float*)d_in[1];
    const float* Qp = (const float*)d_in[2];
    const int*   Mp = (const int*)d_in[3];
    const float* Wf = (const float*)d_in[4];
    const float* bf = (const float*)d_in[5];
    float* Out = (float*)d_out;

    char* p = (char*)d_ws;
    __bf16* Opart = (__bf16*)p;             p += SPLIT * NE * 2;        // 16 MB; X aliases Opart[0]
    float*  Lpart = (float*)p;              p += SPLIT * NL * 4;        // 0.5 MB
    __bf16* Wb    = (__bf16*)p;             p += (size_t)EMB * EMB * 2; // 2 MB
    unsigned long long* Mb = (unsigned long long*)p; p += NMB * 8;      // 1 MB
    __bf16* Kb    = (__bf16*)p;             p += (size_t)1024 * NTILE_ELEMS * 2; // 8 MB
    __bf16* Vtb   = (__bf16*)p;                                         // 8 MB

    prepass_kernel<<<dim3(3072), dim3(256), 0, stream>>>(Kp, Vp, Wf, Mp, Kb, Vtb, Wb, Mb);
    attn_kernel<<<dim3(2 * HEADS * SPLIT * 16), dim3(256), 0, stream>>>(Vtb, Kb, Qp, Mb, Opart, Lpart);
    reduce_kernel<<<dim3(NE / 8 / 256), dim3(256), 0, stream>>>(Opart, Lpart, Opart);
    fc_kernel<<<dim3((2 * S_LEN / 128) * (EMB / 128)), dim3(256), 0, stream>>>(Opart, Wb, bf, Out);
}